// Round 3
// baseline (1356.101 us; speedup 1.0000x reference)
//
#include <hip/hip_runtime.h>
#include <math.h>

#define NSRC 32768
#define NDST 32768
#define NE 524288
#define SRC_D 64
#define DST_D 64
#define EDGE_D 16
#define IN_DIM 144
#define OUT_DIM 128
#define HEADS 8
#define HD 16

// ---------------------------------------------------------------------------
// Fold K-stack layer 2 + q-dot into A[128][8], C[8]:
// scores[e,h] = sum_j hk[e,j]*A[j,h] + C[h]
// A[j,h] = 0.25*( (j in head h ? q[j] : 0) + sum_{d} k_w1[j, h*16+d]*q[h*16+d] )
// C[h]   = 0.25*sum_d q[h*16+d]*k_b1[h*16+d]
// ---------------------------------------------------------------------------
__global__ __launch_bounds__(128) void build_A_kernel(
    const float* __restrict__ q, const float* __restrict__ k_w1,
    const float* __restrict__ k_b1, float* __restrict__ A, float* __restrict__ C)
{
    const int j = threadIdx.x;  // 0..127
    #pragma unroll
    for (int h = 0; h < HEADS; ++h) {
        float s = 0.f;
        #pragma unroll
        for (int d = 0; d < HD; ++d)
            s = fmaf(k_w1[j*OUT_DIM + h*HD + d], q[h*HD + d], s);
        if ((j >> 4) == h) s += q[j];
        A[j*HEADS + h] = 0.25f * s;
    }
    if (j < HEADS) {
        float s = 0.f;
        #pragma unroll
        for (int d = 0; d < HD; ++d) s = fmaf(q[j*HD + d], k_b1[j*HD + d], s);
        C[j] = 0.25f * s;
    }
}

// ---------------------------------------------------------------------------
// One pass over edges: gather x, H=relu(X@[k_w0|v_w0]+b0), V layer-2,
// folded scores, ex=exp(score) (max-subtraction cancels algebraically),
// atomicAdd denom[dst,h] += ex ; acc[dst,c] += ex*v[c].
// 32 edges per 256-thread block.
// ---------------------------------------------------------------------------
__global__ __launch_bounds__(256) void edge_kernel(
    const float* __restrict__ x_src, const float* __restrict__ x_dst,
    const float* __restrict__ e_attr, const int* __restrict__ eidx,
    const float* __restrict__ k_w0, const float* __restrict__ k_b0,
    const float* __restrict__ v_w0, const float* __restrict__ v_b0,
    const float* __restrict__ v_w1, const float* __restrict__ v_b1,
    const float* __restrict__ A, const float* __restrict__ C,
    float* __restrict__ acc_g, float* __restrict__ denom_g)
{
    __shared__ float xs[32][IN_DIM];        // gathered inputs (fp32)
    __shared__ float Hs[32][2*OUT_DIM];     // [.,0:128]=hk, [.,128:256]=hv
    __shared__ float exs[32][HEADS];
    __shared__ int   dsts[32];

    const int t = threadIdx.x;
    const int e0 = blockIdx.x * 32;

    // ---- gather: 8 threads per edge ----
    {
        const int g = t >> 3, l8 = t & 7;
        const int e = e0 + g;
        const int si = eidx[e];
        const int di = eidx[NE + e];
        if (l8 == 0) dsts[g] = di;
        const float4* ps = (const float4*)(x_src + (size_t)si * SRC_D);
        float4 a0 = ps[l8*2+0], a1 = ps[l8*2+1];
        *(float4*)&xs[g][l8*8+0] = a0;
        *(float4*)&xs[g][l8*8+4] = a1;
        const float4* pd = (const float4*)(x_dst + (size_t)di * DST_D);
        float4 b0 = pd[l8*2+0], b1 = pd[l8*2+1];
        *(float4*)&xs[g][SRC_D + l8*8+0] = b0;
        *(float4*)&xs[g][SRC_D + l8*8+4] = b1;
        const float2* pe = (const float2*)(e_attr + (size_t)e * EDGE_D);
        float2 c0 = pe[l8];
        *(float2*)&xs[g][SRC_D + DST_D + l8*2] = c0;
    }
    __syncthreads();

    // ---- GEMM1: thread t owns channel t of [k|v] layer-0 output ----
    {
        const float* __restrict__ W0 = (t < OUT_DIM) ? k_w0 : v_w0;
        const float* __restrict__ B0 = (t < OUT_DIM) ? k_b0 : v_b0;
        const int c = t & (OUT_DIM-1);
        float acc[32];
        #pragma unroll
        for (int e = 0; e < 32; ++e) acc[e] = 0.f;
        for (int i = 0; i < IN_DIM; i += 4) {
            const float w0v = W0[(i+0)*OUT_DIM + c];
            const float w1v = W0[(i+1)*OUT_DIM + c];
            const float w2v = W0[(i+2)*OUT_DIM + c];
            const float w3v = W0[(i+3)*OUT_DIM + c];
            #pragma unroll
            for (int e = 0; e < 32; ++e) {
                const float4 xv = *(const float4*)&xs[e][i];
                acc[e] = fmaf(xv.x, w0v, acc[e]);
                acc[e] = fmaf(xv.y, w1v, acc[e]);
                acc[e] = fmaf(xv.z, w2v, acc[e]);
                acc[e] = fmaf(xv.w, w3v, acc[e]);
            }
        }
        const float bv = B0[c];
        #pragma unroll
        for (int e = 0; e < 32; ++e) {
            Hs[e][t] = fmaxf(acc[e] + bv, 0.f);
        }
    }
    __syncthreads();

    const int cc = t & (OUT_DIM-1);
    const int half = t >> 7;     // edges [half*16, half*16+16)

    // ---- V layer-2 partial: vacc[e2] = sum_j hv[e,j]*v_w1[j,cc] ----
    float vacc[16];
    #pragma unroll
    for (int e2 = 0; e2 < 16; ++e2) vacc[e2] = 0.f;
    for (int j = 0; j < OUT_DIM; j += 4) {
        const float w0v = v_w1[(j+0)*OUT_DIM + cc];
        const float w1v = v_w1[(j+1)*OUT_DIM + cc];
        const float w2v = v_w1[(j+2)*OUT_DIM + cc];
        const float w3v = v_w1[(j+3)*OUT_DIM + cc];
        #pragma unroll
        for (int e2 = 0; e2 < 16; ++e2) {
            const float4 hv = *(const float4*)&Hs[half*16 + e2][OUT_DIM + j];
            vacc[e2] = fmaf(hv.x, w0v, vacc[e2]);
            vacc[e2] = fmaf(hv.y, w1v, vacc[e2]);
            vacc[e2] = fmaf(hv.z, w2v, vacc[e2]);
            vacc[e2] = fmaf(hv.w, w3v, vacc[e2]);
        }
    }

    // ---- scores: one (edge, head) per thread ----
    {
        const int se = t >> 3;
        const int sh = t & 7;
        float s = C[sh];
        for (int j = 0; j < OUT_DIM; j += 4) {
            const float4 hk = *(const float4*)&Hs[se][j];
            s = fmaf(hk.x, A[(j+0)*HEADS + sh], s);
            s = fmaf(hk.y, A[(j+1)*HEADS + sh], s);
            s = fmaf(hk.z, A[(j+2)*HEADS + sh], s);
            s = fmaf(hk.w, A[(j+3)*HEADS + sh], s);
        }
        const float ex = __expf(s);
        exs[se][sh] = ex;
        atomicAdd(&denom_g[(size_t)dsts[se]*HEADS + sh], ex);
    }
    __syncthreads();

    // ---- assemble v and scatter ex*v ----
    {
        const float bv = v_b1[cc];
        #pragma unroll
        for (int e2 = 0; e2 < 16; ++e2) {
            const int e = half*16 + e2;
            const float v = Hs[e][OUT_DIM + cc] + vacc[e2] + bv;
            const float m = exs[e][cc >> 4] * v;
            atomicAdd(&acc_g[(size_t)dsts[e]*OUT_DIM + cc], m);
        }
    }
}

// ---------------------------------------------------------------------------
// Per-dst-node: aggr = acc/denom, relu, then output residual stack.
// 32 nodes per 256-thread block.
// ---------------------------------------------------------------------------
__global__ __launch_bounds__(256) void node_kernel(
    const float* __restrict__ acc_g, const float* __restrict__ denom_g,
    const float* __restrict__ o_w0, const float* __restrict__ o_b0,
    const float* __restrict__ o_w1, const float* __restrict__ o_b1,
    float* __restrict__ out)
{
    __shared__ float as[32][OUT_DIM];
    __shared__ float hs[32][OUT_DIM];
    const int t = threadIdx.x;
    const int n0 = blockIdx.x * 32;

    for (int r = t; r < 32*32; r += 256) {
        const int n = r >> 5, c4 = r & 31;
        float4 a = *(const float4*)&acc_g[(size_t)(n0+n)*OUT_DIM + c4*4];
        const float d = denom_g[(size_t)(n0+n)*HEADS + (c4 >> 2)] + 1e-16f;
        a.x = fmaxf(a.x / d, 0.f);
        a.y = fmaxf(a.y / d, 0.f);
        a.z = fmaxf(a.z / d, 0.f);
        a.w = fmaxf(a.w / d, 0.f);
        *(float4*)&as[n][c4*4] = a;
    }
    __syncthreads();

    const int cc = t & (OUT_DIM-1);
    const int half = t >> 7;
    float hreg[16];
    {
        float acc1[16];
        #pragma unroll
        for (int e2 = 0; e2 < 16; ++e2) acc1[e2] = 0.f;
        for (int j = 0; j < OUT_DIM; j += 4) {
            const float w0v = o_w0[(j+0)*OUT_DIM + cc];
            const float w1v = o_w0[(j+1)*OUT_DIM + cc];
            const float w2v = o_w0[(j+2)*OUT_DIM + cc];
            const float w3v = o_w0[(j+3)*OUT_DIM + cc];
            #pragma unroll
            for (int e2 = 0; e2 < 16; ++e2) {
                const float4 av = *(const float4*)&as[half*16 + e2][j];
                acc1[e2] = fmaf(av.x, w0v, acc1[e2]);
                acc1[e2] = fmaf(av.y, w1v, acc1[e2]);
                acc1[e2] = fmaf(av.z, w2v, acc1[e2]);
                acc1[e2] = fmaf(av.w, w3v, acc1[e2]);
            }
        }
        const float bv = o_b0[cc];
        #pragma unroll
        for (int e2 = 0; e2 < 16; ++e2) {
            float h = fmaxf(acc1[e2] + bv, 0.f);
            hreg[e2] = h;
            hs[half*16 + e2][cc] = h;
        }
    }
    __syncthreads();
    {
        float acc2[16];
        #pragma unroll
        for (int e2 = 0; e2 < 16; ++e2) acc2[e2] = 0.f;
        for (int j = 0; j < OUT_DIM; j += 4) {
            const float w0v = o_w1[(j+0)*OUT_DIM + cc];
            const float w1v = o_w1[(j+1)*OUT_DIM + cc];
            const float w2v = o_w1[(j+2)*OUT_DIM + cc];
            const float w3v = o_w1[(j+3)*OUT_DIM + cc];
            #pragma unroll
            for (int e2 = 0; e2 < 16; ++e2) {
                const float4 hv = *(const float4*)&hs[half*16 + e2][j];
                acc2[e2] = fmaf(hv.x, w0v, acc2[e2]);
                acc2[e2] = fmaf(hv.y, w1v, acc2[e2]);
                acc2[e2] = fmaf(hv.z, w2v, acc2[e2]);
                acc2[e2] = fmaf(hv.w, w3v, acc2[e2]);
            }
        }
        const float bv = o_b1[cc];
        #pragma unroll
        for (int e2 = 0; e2 < 16; ++e2) {
            const int n = n0 + half*16 + e2;
            out[(size_t)n*OUT_DIM + cc] = fmaxf(hreg[e2] + acc2[e2] + bv, 0.f);
        }
    }
}

// ---------------------------------------------------------------------------
extern "C" void kernel_launch(void* const* d_in, const int* in_sizes, int n_in,
                              void* d_out, int out_size, void* d_ws, size_t ws_size,
                              hipStream_t stream) {
    const float* x_src  = (const float*)d_in[0];
    const float* x_dst  = (const float*)d_in[1];
    const float* e_attr = (const float*)d_in[2];
    const int*   eidx   = (const int*)  d_in[3];
    const float* q      = (const float*)d_in[4];
    const float* k_w0   = (const float*)d_in[5];
    const float* k_b0   = (const float*)d_in[6];
    const float* k_w1   = (const float*)d_in[7];
    const float* k_b1   = (const float*)d_in[8];
    const float* v_w0   = (const float*)d_in[9];
    const float* v_b0   = (const float*)d_in[10];
    const float* v_w1   = (const float*)d_in[11];
    const float* v_b1   = (const float*)d_in[12];
    const float* o_w0   = (const float*)d_in[13];
    const float* o_b0   = (const float*)d_in[14];
    const float* o_w1   = (const float*)d_in[15];
    const float* o_b1   = (const float*)d_in[16];
    float* out = (float*)d_out;

    float* acc_g   = (float*)d_ws;                         // NDST*128
    float* denom_g = acc_g + (size_t)NDST*OUT_DIM;         // NDST*8
    float* A       = denom_g + (size_t)NDST*HEADS;         // 128*8
    float* C       = A + 128*HEADS;                        // 8

    // zero the atomic accumulators (ws is poisoned before every launch)
    hipMemsetAsync(d_ws, 0, ((size_t)NDST*OUT_DIM + (size_t)NDST*HEADS)*sizeof(float), stream);

    build_A_kernel<<<1, 128, 0, stream>>>(q, k_w1, k_b1, A, C);
    edge_kernel<<<NE/32, 256, 0, stream>>>(x_src, x_dst, e_attr, eidx,
                                           k_w0, k_b0, v_w0, v_b0, v_w1, v_b1,
                                           A, C, acc_g, denom_g);
    node_kernel<<<NDST/32, 256, 0, stream>>>(acc_g, denom_g,
                                             o_w0, o_b0, o_w1, o_b1, out);
}

// Round 7
// 1224.293 us; speedup vs baseline: 1.1077x; 1.1077x over previous
//
#include <hip/hip_runtime.h>
#include <math.h>

#define NSRC 32768
#define NDST 32768
#define NE 524288
#define SRC_D 64
#define DST_D 64
#define EDGE_D 16
#define IN_DIM 144
#define OUT_DIM 128
#define HEADS 8
#define HD 16

#define HS_LD 264   // Hs leading dim (floats): stride%32==8 -> scores-phase reads 2-way not 8-way

// ---------------------------------------------------------------------------
// Fold K-stack layer 2 + q-dot into A[128][8] (+ transposed copy At[8][128]), C[8]:
// scores[e,h] = sum_j hk[e,j]*A[j,h] + C[h]
// ---------------------------------------------------------------------------
__global__ __launch_bounds__(128) void build_A_kernel(
    const float* __restrict__ q, const float* __restrict__ k_w1,
    const float* __restrict__ k_b1, float* __restrict__ A, float* __restrict__ C,
    float* __restrict__ At)
{
    const int j = threadIdx.x;  // 0..127
    #pragma unroll
    for (int h = 0; h < HEADS; ++h) {
        float s = 0.f;
        #pragma unroll
        for (int d = 0; d < HD; ++d)
            s = fmaf(k_w1[j*OUT_DIM + h*HD + d], q[h*HD + d], s);
        if ((j >> 4) == h) s += q[j];
        const float a = 0.25f * s;
        A[j*HEADS + h] = a;
        At[h*OUT_DIM + j] = a;
    }
    if (j < HEADS) {
        float s = 0.f;
        #pragma unroll
        for (int d = 0; d < HD; ++d) s = fmaf(q[j*HD + d], k_b1[j*HD + d], s);
        C[j] = 0.25f * s;
    }
}

// ---------------------------------------------------------------------------
// Edge pass, register-tiled: each ds_read_b128 feeds 16 FMAs (4ch x 4 i-vals).
// GEMM1: thread -> 4 channels (of 256 = K|V) x 8 edges.
// V2:    thread -> 4 channels (of 128)      x 4 edges.
// 32 edges per 256-thread block.
// ---------------------------------------------------------------------------
__global__ __launch_bounds__(256) void edge_kernel(
    const float* __restrict__ x_src, const float* __restrict__ x_dst,
    const float* __restrict__ e_attr, const int* __restrict__ eidx,
    const float* __restrict__ k_w0, const float* __restrict__ k_b0,
    const float* __restrict__ v_w0, const float* __restrict__ v_b0,
    const float* __restrict__ v_w1, const float* __restrict__ v_b1,
    const float* __restrict__ At, const float* __restrict__ C,
    float* __restrict__ acc_g, float* __restrict__ denom_g)
{
    __shared__ float xs[32][IN_DIM];       // 18432 B
    __shared__ float Hs[32][HS_LD];        // 33792 B  [.,0:128]=hk  [.,128:256]=hv
    __shared__ float exs[32][HEADS];       // 1024 B
    __shared__ int   dsts[32];

    const int t = threadIdx.x;
    const int e0 = blockIdx.x * 32;

    // ---- gather: 8 threads per edge ----
    {
        const int g = t >> 3, l8 = t & 7;
        const int e = e0 + g;
        const int si = eidx[e];
        const int di = eidx[NE + e];
        if (l8 == 0) dsts[g] = di;
        const float4* ps = (const float4*)(x_src + (size_t)si * SRC_D);
        float4 a0 = ps[l8*2+0], a1 = ps[l8*2+1];
        *(float4*)&xs[g][l8*8+0] = a0;
        *(float4*)&xs[g][l8*8+4] = a1;
        const float4* pd = (const float4*)(x_dst + (size_t)di * DST_D);
        float4 b0 = pd[l8*2+0], b1 = pd[l8*2+1];
        *(float4*)&xs[g][SRC_D + l8*8+0] = b0;
        *(float4*)&xs[g][SRC_D + l8*8+4] = b1;
        const float2* pe = (const float2*)(e_attr + (size_t)e * EDGE_D);
        float2 c0v = pe[l8];
        *(float2*)&xs[g][SRC_D + DST_D + l8*2] = c0v;
    }
    __syncthreads();

    // ---- GEMM1: H[e][c] = relu(sum_i x[e][i]*W0[i][c] + b0[c]) ----
    // thread t: channels c0..c0+3 (c0 = (t&63)*4 of 256 concat K|V), edges g*8..g*8+7 (g=t>>6).
    // Per wave g is uniform -> xs reads are pure broadcast.
    {
        const int cq = t & 63;
        const int c0 = cq * 4;
        const int g  = t >> 6;
        const bool isK = (c0 < OUT_DIM);
        const float4* __restrict__ Wf4 =
            (const float4*)(isK ? k_w0 : v_w0) + ((isK ? c0 : c0 - OUT_DIM) >> 2);
        const float4 bias = *((const float4*)(isK ? k_b0 : v_b0) + ((isK ? c0 : c0 - OUT_DIM) >> 2));

        float4 acc[8];
        #pragma unroll
        for (int e = 0; e < 8; ++e) acc[e] = make_float4(0.f, 0.f, 0.f, 0.f);

        #pragma unroll 4
        for (int i = 0; i < IN_DIM; i += 4) {
            const float4 wa = Wf4[(i+0) * (OUT_DIM/4)];
            const float4 wb = Wf4[(i+1) * (OUT_DIM/4)];
            const float4 wc = Wf4[(i+2) * (OUT_DIM/4)];
            const float4 wd = Wf4[(i+3) * (OUT_DIM/4)];
            #pragma unroll
            for (int e = 0; e < 8; ++e) {
                const float4 xv = *(const float4*)&xs[g*8 + e][i];
                acc[e].x = fmaf(xv.x, wa.x, acc[e].x);
                acc[e].y = fmaf(xv.x, wa.y, acc[e].y);
                acc[e].z = fmaf(xv.x, wa.z, acc[e].z);
                acc[e].w = fmaf(xv.x, wa.w, acc[e].w);
                acc[e].x = fmaf(xv.y, wb.x, acc[e].x);
                acc[e].y = fmaf(xv.y, wb.y, acc[e].y);
                acc[e].z = fmaf(xv.y, wb.z, acc[e].z);
                acc[e].w = fmaf(xv.y, wb.w, acc[e].w);
                acc[e].x = fmaf(xv.z, wc.x, acc[e].x);
                acc[e].y = fmaf(xv.z, wc.y, acc[e].y);
                acc[e].z = fmaf(xv.z, wc.z, acc[e].z);
                acc[e].w = fmaf(xv.z, wc.w, acc[e].w);
                acc[e].x = fmaf(xv.w, wd.x, acc[e].x);
                acc[e].y = fmaf(xv.w, wd.y, acc[e].y);
                acc[e].z = fmaf(xv.w, wd.z, acc[e].z);
                acc[e].w = fmaf(xv.w, wd.w, acc[e].w);
            }
        }
        #pragma unroll
        for (int e = 0; e < 8; ++e) {
            float4 h;
            h.x = fmaxf(acc[e].x + bias.x, 0.f);
            h.y = fmaxf(acc[e].y + bias.y, 0.f);
            h.z = fmaxf(acc[e].z + bias.z, 0.f);
            h.w = fmaxf(acc[e].w + bias.w, 0.f);
            *(float4*)&Hs[g*8 + e][c0] = h;
        }
    }
    __syncthreads();

    // ---- V2 partials: vacc[e][c] = sum_j hv[e][j]*v_w1[j][c]  (4 edges x 4 ch) ----
    const int cq2 = t & 31;
    const int c0v = cq2 * 4;          // V channel 0..124
    const int g2  = t >> 5;           // edge group 0..7 -> edges g2*4..g2*4+3
    float4 vacc[4];
    {
        const float4* __restrict__ Vf4 = (const float4*)v_w1 + cq2;
        #pragma unroll
        for (int e = 0; e < 4; ++e) vacc[e] = make_float4(0.f, 0.f, 0.f, 0.f);
        #pragma unroll 4
        for (int j = 0; j < OUT_DIM; j += 4) {
            const float4 wa = Vf4[(j+0) * (OUT_DIM/4)];
            const float4 wb = Vf4[(j+1) * (OUT_DIM/4)];
            const float4 wc = Vf4[(j+2) * (OUT_DIM/4)];
            const float4 wd = Vf4[(j+3) * (OUT_DIM/4)];
            #pragma unroll
            for (int e = 0; e < 4; ++e) {
                const float4 hv = *(const float4*)&Hs[g2*4 + e][OUT_DIM + j];
                vacc[e].x = fmaf(hv.x, wa.x, vacc[e].x);
                vacc[e].y = fmaf(hv.x, wa.y, vacc[e].y);
                vacc[e].z = fmaf(hv.x, wa.z, vacc[e].z);
                vacc[e].w = fmaf(hv.x, wa.w, vacc[e].w);
                vacc[e].x = fmaf(hv.y, wb.x, vacc[e].x);
                vacc[e].y = fmaf(hv.y, wb.y, vacc[e].y);
                vacc[e].z = fmaf(hv.y, wb.z, vacc[e].z);
                vacc[e].w = fmaf(hv.y, wb.w, vacc[e].w);
                vacc[e].x = fmaf(hv.z, wc.x, vacc[e].x);
                vacc[e].y = fmaf(hv.z, wc.y, vacc[e].y);
                vacc[e].z = fmaf(hv.z, wc.z, vacc[e].z);
                vacc[e].w = fmaf(hv.z, wc.w, vacc[e].w);
                vacc[e].x = fmaf(hv.w, wd.x, vacc[e].x);
                vacc[e].y = fmaf(hv.w, wd.y, vacc[e].y);
                vacc[e].z = fmaf(hv.w, wd.z, vacc[e].z);
                vacc[e].w = fmaf(hv.w, wd.w, vacc[e].w);
            }
        }
    }

    // ---- scores: one (edge, head) per thread; Hs stride 264 -> 2-way reads ----
    {
        const int se = t >> 3;
        const int sh = t & 7;
        const float4* __restrict__ At4 = (const float4*)(At + sh * OUT_DIM);
        float s = C[sh];
        #pragma unroll 4
        for (int j = 0; j < OUT_DIM; j += 4) {
            const float4 hk = *(const float4*)&Hs[se][j];
            const float4 av = At4[j >> 2];
            s = fmaf(hk.x, av.x, s);
            s = fmaf(hk.y, av.y, s);
            s = fmaf(hk.z, av.z, s);
            s = fmaf(hk.w, av.w, s);
        }
        const float ex = __expf(s);
        exs[se][sh] = ex;
        atomicAdd(&denom_g[(size_t)dsts[se]*HEADS + sh], ex);
    }
    __syncthreads();

    // ---- assemble v (residual + bias) and scatter ex*v ----
    {
        const float4 bv = *((const float4*)v_b1 + cq2);
        const int h = c0v >> 4;                    // head for channels c0v..c0v+3
        #pragma unroll
        for (int e = 0; e < 4; ++e) {
            const int ee = g2*4 + e;
            const float4 hv = *(const float4*)&Hs[ee][OUT_DIM + c0v];
            const float ex = exs[ee][h];
            const size_t base = (size_t)dsts[ee]*OUT_DIM + c0v;
            atomicAdd(&acc_g[base+0], ex * (hv.x + vacc[e].x + bv.x));
            atomicAdd(&acc_g[base+1], ex * (hv.y + vacc[e].y + bv.y));
            atomicAdd(&acc_g[base+2], ex * (hv.z + vacc[e].z + bv.z));
            atomicAdd(&acc_g[base+3], ex * (hv.w + vacc[e].w + bv.w));
        }
    }
}

// ---------------------------------------------------------------------------
// Per-dst-node: aggr = acc/denom, relu, then output residual stack.
// 32 nodes per 256-thread block.
// ---------------------------------------------------------------------------
__global__ __launch_bounds__(256) void node_kernel(
    const float* __restrict__ acc_g, const float* __restrict__ denom_g,
    const float* __restrict__ o_w0, const float* __restrict__ o_b0,
    const float* __restrict__ o_w1, const float* __restrict__ o_b1,
    float* __restrict__ out)
{
    __shared__ float as[32][OUT_DIM];
    __shared__ float hs[32][OUT_DIM];
    const int t = threadIdx.x;
    const int n0 = blockIdx.x * 32;

    for (int r = t; r < 32*32; r += 256) {
        const int n = r >> 5, c4 = r & 31;
        float4 a = *(const float4*)&acc_g[(size_t)(n0+n)*OUT_DIM + c4*4];
        const float d = denom_g[(size_t)(n0+n)*HEADS + (c4 >> 2)] + 1e-16f;
        a.x = fmaxf(a.x / d, 0.f);
        a.y = fmaxf(a.y / d, 0.f);
        a.z = fmaxf(a.z / d, 0.f);
        a.w = fmaxf(a.w / d, 0.f);
        *(float4*)&as[n][c4*4] = a;
    }
    __syncthreads();

    const int cc = t & (OUT_DIM-1);
    const int half = t >> 7;
    float hreg[16];
    {
        float acc1[16];
        #pragma unroll
        for (int e2 = 0; e2 < 16; ++e2) acc1[e2] = 0.f;
        for (int j = 0; j < OUT_DIM; j += 4) {
            const float w0v = o_w0[(j+0)*OUT_DIM + cc];
            const float w1v = o_w0[(j+1)*OUT_DIM + cc];
            const float w2v = o_w0[(j+2)*OUT_DIM + cc];
            const float w3v = o_w0[(j+3)*OUT_DIM + cc];
            #pragma unroll
            for (int e2 = 0; e2 < 16; ++e2) {
                const float4 av = *(const float4*)&as[half*16 + e2][j];
                acc1[e2] = fmaf(av.x, w0v, acc1[e2]);
                acc1[e2] = fmaf(av.y, w1v, acc1[e2]);
                acc1[e2] = fmaf(av.z, w2v, acc1[e2]);
                acc1[e2] = fmaf(av.w, w3v, acc1[e2]);
            }
        }
        const float bv = o_b0[cc];
        #pragma unroll
        for (int e2 = 0; e2 < 16; ++e2) {
            float h = fmaxf(acc1[e2] + bv, 0.f);
            hreg[e2] = h;
            hs[half*16 + e2][cc] = h;
        }
    }
    __syncthreads();
    {
        float acc2[16];
        #pragma unroll
        for (int e2 = 0; e2 < 16; ++e2) acc2[e2] = 0.f;
        for (int j = 0; j < OUT_DIM; j += 4) {
            const float w0v = o_w1[(j+0)*OUT_DIM + cc];
            const float w1v = o_w1[(j+1)*OUT_DIM + cc];
            const float w2v = o_w1[(j+2)*OUT_DIM + cc];
            const float w3v = o_w1[(j+3)*OUT_DIM + cc];
            #pragma unroll
            for (int e2 = 0; e2 < 16; ++e2) {
                const float4 hv = *(const float4*)&hs[half*16 + e2][j];
                acc2[e2] = fmaf(hv.x, w0v, acc2[e2]);
                acc2[e2] = fmaf(hv.y, w1v, acc2[e2]);
                acc2[e2] = fmaf(hv.z, w2v, acc2[e2]);
                acc2[e2] = fmaf(hv.w, w3v, acc2[e2]);
            }
        }
        const float bv = o_b1[cc];
        #pragma unroll
        for (int e2 = 0; e2 < 16; ++e2) {
            const int n = n0 + half*16 + e2;
            out[(size_t)n*OUT_DIM + cc] = fmaxf(hreg[e2] + acc2[e2] + bv, 0.f);
        }
    }
}

// ---------------------------------------------------------------------------
extern "C" void kernel_launch(void* const* d_in, const int* in_sizes, int n_in,
                              void* d_out, int out_size, void* d_ws, size_t ws_size,
                              hipStream_t stream) {
    const float* x_src  = (const float*)d_in[0];
    const float* x_dst  = (const float*)d_in[1];
    const float* e_attr = (const float*)d_in[2];
    const int*   eidx   = (const int*)  d_in[3];
    const float* q      = (const float*)d_in[4];
    const float* k_w0   = (const float*)d_in[5];
    const float* k_b0   = (const float*)d_in[6];
    const float* k_w1   = (const float*)d_in[7];
    const float* k_b1   = (const float*)d_in[8];
    const float* v_w0   = (const float*)d_in[9];
    const float* v_b0   = (const float*)d_in[10];
    const float* v_w1   = (const float*)d_in[11];
    const float* v_b1   = (const float*)d_in[12];
    const float* o_w0   = (const float*)d_in[13];
    const float* o_b0   = (const float*)d_in[14];
    const float* o_w1   = (const float*)d_in[15];
    const float* o_b1   = (const float*)d_in[16];
    float* out = (float*)d_out;

    float* acc_g   = (float*)d_ws;                         // NDST*128
    float* denom_g = acc_g + (size_t)NDST*OUT_DIM;         // NDST*8
    float* A       = denom_g + (size_t)NDST*HEADS;         // 128*8
    float* C       = A + 128*HEADS;                        // 8
    float* At      = C + 8;                                // 8*128

    // zero the atomic accumulators (ws is poisoned before every launch)
    hipMemsetAsync(d_ws, 0, ((size_t)NDST*OUT_DIM + (size_t)NDST*HEADS)*sizeof(float), stream);

    build_A_kernel<<<1, 128, 0, stream>>>(q, k_w1, k_b1, A, C, At);
    edge_kernel<<<NE/32, 256, 0, stream>>>(x_src, x_dst, e_attr, eidx,
                                           k_w0, k_b0, v_w0, v_b0, v_w1, v_b1,
                                           At, C, acc_g, denom_g);
    node_kernel<<<NDST/32, 256, 0, stream>>>(acc_g, denom_g,
                                             o_w0, o_b0, o_w1, o_b1, out);
}

// Round 12
// 1165.598 us; speedup vs baseline: 1.1634x; 1.0504x over previous
//
#include <hip/hip_runtime.h>
#include <math.h>

#define NSRC 32768
#define NDST 32768
#define NE 524288
#define SRC_D 64
#define DST_D 64
#define EDGE_D 16
#define IN_DIM 144
#define OUT_DIM 128
#define HEADS 8
#define HD 16

#define HS_LD 264    // Hs leading dim (floats)
#define K_PAD 168    // A-plane leading dim (bf16 elems): 144 real + 16 zero-pad (k<160) + 8 stagger
#define NKS 5        // K-steps of 32 (160 = 5*32, zero-padded from 144)

typedef __attribute__((ext_vector_type(8))) short short8;   // 8 bf16 (4 VGPRs) MFMA A/B frag
typedef __attribute__((ext_vector_type(4))) float f32x4;    // MFMA C/D frag

__device__ __forceinline__ ushort bf_hi(float x) {
    uint u = __float_as_uint(x);
    return (ushort)((u + 0x7FFF + ((u >> 16) & 1)) >> 16);   // RNE bf16
}
__device__ __forceinline__ float bf_f(ushort h) { return __uint_as_float(((uint)h) << 16); }

// pack 8 floats -> hi/lo bf16 planes (as uint4 each)
__device__ __forceinline__ void pack8(const float* v, uint4* phi, uint4* plo) {
    ushort h[8], l[8];
    #pragma unroll
    for (int j = 0; j < 8; ++j) {
        h[j] = bf_hi(v[j]);
        l[j] = bf_hi(v[j] - bf_f(h[j]));
    }
    phi->x = (uint)h[0] | ((uint)h[1] << 16);
    phi->y = (uint)h[2] | ((uint)h[3] << 16);
    phi->z = (uint)h[4] | ((uint)h[5] << 16);
    phi->w = (uint)h[6] | ((uint)h[7] << 16);
    plo->x = (uint)l[0] | ((uint)l[1] << 16);
    plo->y = (uint)l[2] | ((uint)l[3] << 16);
    plo->z = (uint)l[4] | ((uint)l[5] << 16);
    plo->w = (uint)l[6] | ((uint)l[7] << 16);
}

// ---------------------------------------------------------------------------
// Fold K-stack layer 2 + q-dot into At[8][128], C[8]:
// scores[e,h] = sum_j hk[e,j]*At[h][j] + C[h]
// ---------------------------------------------------------------------------
__global__ __launch_bounds__(128) void build_A_kernel(
    const float* __restrict__ q, const float* __restrict__ k_w1,
    const float* __restrict__ k_b1, float* __restrict__ C, float* __restrict__ At)
{
    const int j = threadIdx.x;  // 0..127
    #pragma unroll
    for (int h = 0; h < HEADS; ++h) {
        float s = 0.f;
        #pragma unroll
        for (int d = 0; d < HD; ++d)
            s = fmaf(k_w1[j*OUT_DIM + h*HD + d], q[h*HD + d], s);
        if ((j >> 4) == h) s += q[j];
        At[h*OUT_DIM + j] = 0.25f * s;
    }
    if (j < HEADS) {
        float s = 0.f;
        #pragma unroll
        for (int d = 0; d < HD; ++d) s = fmaf(q[j*HD + d], k_b1[j*HD + d], s);
        C[j] = 0.25f * s;
    }
}

// ---------------------------------------------------------------------------
// Pre-pack B = [k_w0 | v_w0] (144x256, zero-pad k to 160) into per-lane MFMA
// fragment order, split bf16 hi/lo.  frag (ntg 0..15, ks 0..4, lane 0..63):
// elem j (0..7): B[k = ks*32 + (lane>>4)*8 + j][ch = ntg*16 + (lane&15)]
// ---------------------------------------------------------------------------
__global__ __launch_bounds__(256) void prepack_B_kernel(
    const float* __restrict__ k_w0, const float* __restrict__ v_w0,
    uint4* __restrict__ bhi, uint4* __restrict__ blo)
{
    const int tid = blockIdx.x * 256 + threadIdx.x;
    const int fg = tid >> 6;          // 0..79
    if (fg >= 16 * NKS) return;
    const int lane = tid & 63;
    const int ntg = fg / NKS, ks = fg % NKS;
    const int ch = ntg * 16 + (lane & 15);
    const int kb = ks * 32 + (lane >> 4) * 8;
    float v[8];
    #pragma unroll
    for (int j = 0; j < 8; ++j) {
        const int k = kb + j;
        v[j] = (k < IN_DIM) ? (ch < OUT_DIM ? k_w0[k*OUT_DIM + ch]
                                            : v_w0[k*OUT_DIM + ch - OUT_DIM])
                            : 0.f;
    }
    uint4 h4, l4;
    pack8(v, &h4, &l4);
    bhi[fg*64 + lane] = h4;
    blo[fg*64 + lane] = l4;
}

// ---------------------------------------------------------------------------
// Edge pass: gather -> bf16-split A planes; GEMM1 via MFMA (split-bf16, ~fp32
// accuracy); V2 / scores / scatter identical to the verified fp32 code.
// 32 edges per 256-thread block (4 waves).
// ---------------------------------------------------------------------------
__global__ __launch_bounds__(256, 2) void edge_kernel(
    const float* __restrict__ x_src, const float* __restrict__ x_dst,
    const float* __restrict__ e_attr, const int* __restrict__ eidx,
    const float* __restrict__ k_b0, const float* __restrict__ v_b0,
    const float* __restrict__ v_w1, const float* __restrict__ v_b1,
    const uint4* __restrict__ Bph, const uint4* __restrict__ Bpl,
    const float* __restrict__ At, const float* __restrict__ C,
    float* __restrict__ acc_g, float* __restrict__ denom_g)
{
    __shared__ ushort Ah[32][K_PAD];       // 10752 B  bf16 hi plane of gathered x
    __shared__ ushort Al[32][K_PAD];       // 10752 B  bf16 lo plane
    __shared__ float Hs[32][HS_LD];        // 33792 B  [.,0:128]=hk  [.,128:256]=hv
    __shared__ float exs[32][HEADS];       // 1024 B
    __shared__ int   dsts[32];

    const int t = threadIdx.x;
    const int e0 = blockIdx.x * 32;

    // ---- gather: 8 threads per edge; convert fp32 -> bf16 hi/lo planes ----
    {
        const int g = t >> 3, l8 = t & 7;
        const int e = e0 + g;
        const int si = eidx[e];
        const int di = eidx[NE + e];
        if (l8 == 0) dsts[g] = di;
        float v8[8];
        uint4 h4, l4;
        // src: 8 floats at k = l8*8
        {
            const float4* ps = (const float4*)(x_src + (size_t)si * SRC_D);
            float4 a0 = ps[l8*2+0], a1 = ps[l8*2+1];
            v8[0]=a0.x; v8[1]=a0.y; v8[2]=a0.z; v8[3]=a0.w;
            v8[4]=a1.x; v8[5]=a1.y; v8[6]=a1.z; v8[7]=a1.w;
            pack8(v8, &h4, &l4);
            *(uint4*)&Ah[g][l8*8] = h4;
            *(uint4*)&Al[g][l8*8] = l4;
        }
        // dst: 8 floats at k = 64 + l8*8
        {
            const float4* pd = (const float4*)(x_dst + (size_t)di * DST_D);
            float4 b0 = pd[l8*2+0], b1 = pd[l8*2+1];
            v8[0]=b0.x; v8[1]=b0.y; v8[2]=b0.z; v8[3]=b0.w;
            v8[4]=b1.x; v8[5]=b1.y; v8[6]=b1.z; v8[7]=b1.w;
            pack8(v8, &h4, &l4);
            *(uint4*)&Ah[g][SRC_D + l8*8] = h4;
            *(uint4*)&Al[g][SRC_D + l8*8] = l4;
        }
        // edge_attr: 2 floats at k = 128 + l8*2
        {
            const float2* pe = (const float2*)(e_attr + (size_t)e * EDGE_D);
            float2 c2 = pe[l8];
            ushort h0 = bf_hi(c2.x), h1 = bf_hi(c2.y);
            ushort l0 = bf_hi(c2.x - bf_f(h0)), l1 = bf_hi(c2.y - bf_f(h1));
            *(uint*)&Ah[g][SRC_D + DST_D + l8*2] = (uint)h0 | ((uint)h1 << 16);
            *(uint*)&Al[g][SRC_D + DST_D + l8*2] = (uint)l0 | ((uint)l1 << 16);
        }
        // zero-pad k = 144..159 (16 elems, 2 threads x 8)
        if (l8 < 2) {
            const uint4 z = make_uint4(0u, 0u, 0u, 0u);
            *(uint4*)&Ah[g][IN_DIM + l8*8] = z;
            *(uint4*)&Al[g][IN_DIM + l8*8] = z;
        }
    }
    __syncthreads();

    // ---- GEMM1 via MFMA: H[32][256] = relu(X[32][144] @ [k_w0|v_w0] + b0) ----
    // wave w owns ntiles w*4..w*4+3 (64 channels); 2 m-tiles (32 edges).
    // split-bf16: acc += a_lo*b_hi + a_hi*b_lo + a_hi*b_hi  (~fp32 accuracy)
    {
        const int w = t >> 6, l = t & 63;
        const int r16 = l & 15, kq = l >> 4;
        f32x4 acc[4][2];
        #pragma unroll
        for (int nt = 0; nt < 4; ++nt) {
            acc[nt][0] = (f32x4){0.f, 0.f, 0.f, 0.f};
            acc[nt][1] = (f32x4){0.f, 0.f, 0.f, 0.f};
        }
        #pragma unroll
        for (int ks = 0; ks < NKS; ++ks) {
            const int koff = ks*32 + kq*8;
            const short8 ah0 = *(const short8*)&Ah[r16][koff];
            const short8 al0 = *(const short8*)&Al[r16][koff];
            const short8 ah1 = *(const short8*)&Ah[16 + r16][koff];
            const short8 al1 = *(const short8*)&Al[16 + r16][koff];
            #pragma unroll
            for (int nt = 0; nt < 4; ++nt) {
                const int fg = ((w*4 + nt)*NKS + ks)*64 + l;
                const short8 bh = *(const short8*)&Bph[fg];
                const short8 bl = *(const short8*)&Bpl[fg];
                acc[nt][0] = __builtin_amdgcn_mfma_f32_16x16x32_bf16(al0, bh, acc[nt][0], 0, 0, 0);
                acc[nt][0] = __builtin_amdgcn_mfma_f32_16x16x32_bf16(ah0, bl, acc[nt][0], 0, 0, 0);
                acc[nt][0] = __builtin_amdgcn_mfma_f32_16x16x32_bf16(ah0, bh, acc[nt][0], 0, 0, 0);
                acc[nt][1] = __builtin_amdgcn_mfma_f32_16x16x32_bf16(al1, bh, acc[nt][1], 0, 0, 0);
                acc[nt][1] = __builtin_amdgcn_mfma_f32_16x16x32_bf16(ah1, bl, acc[nt][1], 0, 0, 0);
                acc[nt][1] = __builtin_amdgcn_mfma_f32_16x16x32_bf16(ah1, bh, acc[nt][1], 0, 0, 0);
            }
        }
        // epilogue: bias + relu, write to Hs.  D layout: col=l&15, row=(l>>4)*4+r
        #pragma unroll
        for (int nt = 0; nt < 4; ++nt) {
            const int ch = (w*4 + nt)*16 + r16;
            const float bias = (ch < OUT_DIM) ? k_b0[ch] : v_b0[ch - OUT_DIM];
            #pragma unroll
            for (int mt = 0; mt < 2; ++mt) {
                #pragma unroll
                for (int r = 0; r < 4; ++r) {
                    const int edge = mt*16 + kq*4 + r;
                    Hs[edge][ch] = fmaxf(acc[nt][mt][r] + bias, 0.f);
                }
            }
        }
    }
    __syncthreads();

    // ---- V2 partials: vacc[e][c] = sum_j hv[e][j]*v_w1[j][c]  (4 edges x 4 ch) ----
    const int cq2 = t & 31;
    const int c0v = cq2 * 4;          // V channel 0..124
    const int g2  = t >> 5;           // edge group 0..7 -> edges g2*4..g2*4+3
    float4 vacc[4];
    {
        const float4* __restrict__ Vf4 = (const float4*)v_w1 + cq2;
        #pragma unroll
        for (int e = 0; e < 4; ++e) vacc[e] = make_float4(0.f, 0.f, 0.f, 0.f);
        #pragma unroll 4
        for (int j = 0; j < OUT_DIM; j += 4) {
            const float4 wa = Vf4[(j+0) * (OUT_DIM/4)];
            const float4 wb = Vf4[(j+1) * (OUT_DIM/4)];
            const float4 wc = Vf4[(j+2) * (OUT_DIM/4)];
            const float4 wd = Vf4[(j+3) * (OUT_DIM/4)];
            #pragma unroll
            for (int e = 0; e < 4; ++e) {
                const float4 hv = *(const float4*)&Hs[g2*4 + e][OUT_DIM + j];
                vacc[e].x = fmaf(hv.x, wa.x, vacc[e].x);
                vacc[e].y = fmaf(hv.x, wa.y, vacc[e].y);
                vacc[e].z = fmaf(hv.x, wa.z, vacc[e].z);
                vacc[e].w = fmaf(hv.x, wa.w, vacc[e].w);
                vacc[e].x = fmaf(hv.y, wb.x, vacc[e].x);
                vacc[e].y = fmaf(hv.y, wb.y, vacc[e].y);
                vacc[e].z = fmaf(hv.y, wb.z, vacc[e].z);
                vacc[e].w = fmaf(hv.y, wb.w, vacc[e].w);
                vacc[e].x = fmaf(hv.z, wc.x, vacc[e].x);
                vacc[e].y = fmaf(hv.z, wc.y, vacc[e].y);
                vacc[e].z = fmaf(hv.z, wc.z, vacc[e].z);
                vacc[e].w = fmaf(hv.z, wc.w, vacc[e].w);
                vacc[e].x = fmaf(hv.w, wd.x, vacc[e].x);
                vacc[e].y = fmaf(hv.w, wd.y, vacc[e].y);
                vacc[e].z = fmaf(hv.w, wd.z, vacc[e].z);
                vacc[e].w = fmaf(hv.w, wd.w, vacc[e].w);
            }
        }
    }

    // ---- scores: one (edge, head) per thread ----
    {
        const int se = t >> 3;
        const int sh = t & 7;
        const float4* __restrict__ At4 = (const float4*)(At + sh * OUT_DIM);
        float s = C[sh];
        #pragma unroll 4
        for (int j = 0; j < OUT_DIM; j += 4) {
            const float4 hk = *(const float4*)&Hs[se][j];
            const float4 av = At4[j >> 2];
            s = fmaf(hk.x, av.x, s);
            s = fmaf(hk.y, av.y, s);
            s = fmaf(hk.z, av.z, s);
            s = fmaf(hk.w, av.w, s);
        }
        const float ex = __expf(s);
        exs[se][sh] = ex;
        atomicAdd(&denom_g[(size_t)dsts[se]*HEADS + sh], ex);
    }
    __syncthreads();

    // ---- assemble v (residual + bias) and scatter ex*v ----
    {
        const float4 bv = *((const float4*)v_b1 + cq2);
        const int h = c0v >> 4;                    // head for channels c0v..c0v+3
        #pragma unroll
        for (int e = 0; e < 4; ++e) {
            const int ee = g2*4 + e;
            const float4 hv = *(const float4*)&Hs[ee][OUT_DIM + c0v];
            const float ex = exs[ee][h];
            const size_t base = (size_t)dsts[ee]*OUT_DIM + c0v;
            atomicAdd(&acc_g[base+0], ex * (hv.x + vacc[e].x + bv.x));
            atomicAdd(&acc_g[base+1], ex * (hv.y + vacc[e].y + bv.y));
            atomicAdd(&acc_g[base+2], ex * (hv.z + vacc[e].z + bv.z));
            atomicAdd(&acc_g[base+3], ex * (hv.w + vacc[e].w + bv.w));
        }
    }
}

// ---------------------------------------------------------------------------
// Per-dst-node: aggr = acc/denom, relu, then output residual stack.
// 32 nodes per 256-thread block.
// ---------------------------------------------------------------------------
__global__ __launch_bounds__(256) void node_kernel(
    const float* __restrict__ acc_g, const float* __restrict__ denom_g,
    const float* __restrict__ o_w0, const float* __restrict__ o_b0,
    const float* __restrict__ o_w1, const float* __restrict__ o_b1,
    float* __restrict__ out)
{
    __shared__ float as[32][OUT_DIM];
    __shared__ float hs[32][OUT_DIM];
    const int t = threadIdx.x;
    const int n0 = blockIdx.x * 32;

    for (int r = t; r < 32*32; r += 256) {
        const int n = r >> 5, c4 = r & 31;
        float4 a = *(const float4*)&acc_g[(size_t)(n0+n)*OUT_DIM + c4*4];
        const float d = denom_g[(size_t)(n0+n)*HEADS + (c4 >> 2)] + 1e-16f;
        a.x = fmaxf(a.x / d, 0.f);
        a.y = fmaxf(a.y / d, 0.f);
        a.z = fmaxf(a.z / d, 0.f);
        a.w = fmaxf(a.w / d, 0.f);
        *(float4*)&as[n][c4*4] = a;
    }
    __syncthreads();

    const int cc = t & (OUT_DIM-1);
    const int half = t >> 7;
    float hreg[16];
    {
        float acc1[16];
        #pragma unroll
        for (int e2 = 0; e2 < 16; ++e2) acc1[e2] = 0.f;
        for (int j = 0; j < OUT_DIM; j += 4) {
            const float w0v = o_w0[(j+0)*OUT_DIM + cc];
            const float w1v = o_w0[(j+1)*OUT_DIM + cc];
            const float w2v = o_w0[(j+2)*OUT_DIM + cc];
            const float w3v = o_w0[(j+3)*OUT_DIM + cc];
            #pragma unroll
            for (int e2 = 0; e2 < 16; ++e2) {
                const float4 av = *(const float4*)&as[half*16 + e2][j];
                acc1[e2] = fmaf(av.x, w0v, acc1[e2]);
                acc1[e2] = fmaf(av.y, w1v, acc1[e2]);
                acc1[e2] = fmaf(av.z, w2v, acc1[e2]);
                acc1[e2] = fmaf(av.w, w3v, acc1[e2]);
            }
        }
        const float bv = o_b0[cc];
        #pragma unroll
        for (int e2 = 0; e2 < 16; ++e2) {
            float h = fmaxf(acc1[e2] + bv, 0.f);
            hreg[e2] = h;
            hs[half*16 + e2][cc] = h;
        }
    }
    __syncthreads();
    {
        float acc2[16];
        #pragma unroll
        for (int e2 = 0; e2 < 16; ++e2) acc2[e2] = 0.f;
        for (int j = 0; j < OUT_DIM; j += 4) {
            const float w0v = o_w1[(j+0)*OUT_DIM + cc];
            const float w1v = o_w1[(j+1)*OUT_DIM + cc];
            const float w2v = o_w1[(j+2)*OUT_DIM + cc];
            const float w3v = o_w1[(j+3)*OUT_DIM + cc];
            #pragma unroll
            for (int e2 = 0; e2 < 16; ++e2) {
                const float4 hv = *(const float4*)&hs[half*16 + e2][j];
                acc2[e2] = fmaf(hv.x, w0v, acc2[e2]);
                acc2[e2] = fmaf(hv.y, w1v, acc2[e2]);
                acc2[e2] = fmaf(hv.z, w2v, acc2[e2]);
                acc2[e2] = fmaf(hv.w, w3v, acc2[e2]);
            }
        }
        const float bv = o_b1[cc];
        #pragma unroll
        for (int e2 = 0; e2 < 16; ++e2) {
            const int n = n0 + half*16 + e2;
            out[(size_t)n*OUT_DIM + cc] = fmaxf(hreg[e2] + acc2[e2] + bv, 0.f);
        }
    }
}

// ---------------------------------------------------------------------------
extern "C" void kernel_launch(void* const* d_in, const int* in_sizes, int n_in,
                              void* d_out, int out_size, void* d_ws, size_t ws_size,
                              hipStream_t stream) {
    const float* x_src  = (const float*)d_in[0];
    const float* x_dst  = (const float*)d_in[1];
    const float* e_attr = (const float*)d_in[2];
    const int*   eidx   = (const int*)  d_in[3];
    const float* q      = (const float*)d_in[4];
    const float* k_w0   = (const float*)d_in[5];
    const float* k_b0   = (const float*)d_in[6];
    const float* k_w1   = (const float*)d_in[7];
    const float* k_b1   = (const float*)d_in[8];
    const float* v_w0   = (const float*)d_in[9];
    const float* v_b0   = (const float*)d_in[10];
    const float* v_w1   = (const float*)d_in[11];
    const float* v_b1   = (const float*)d_in[12];
    const float* o_w0   = (const float*)d_in[13];
    const float* o_b0   = (const float*)d_in[14];
    const float* o_w1   = (const float*)d_in[15];
    const float* o_b1   = (const float*)d_in[16];
    float* out = (float*)d_out;

    float* acc_g   = (float*)d_ws;                         // NDST*128 floats
    float* denom_g = acc_g + (size_t)NDST*OUT_DIM;         // NDST*8
    float* C       = denom_g + (size_t)NDST*HEADS;         // 8
    float* At      = C + 8;                                // 8*128
    // B fragment packs (16B aligned): 80 frag-groups x 64 lanes x 16 B, hi+lo
    size_t boff = ((size_t)NDST*OUT_DIM + (size_t)NDST*HEADS + 8 + 8*OUT_DIM + 3) & ~(size_t)3;
    uint4* Bph = (uint4*)((float*)d_ws + boff);
    uint4* Bpl = Bph + 16*NKS*64;

    // zero the atomic accumulators (ws is poisoned before every launch)
    hipMemsetAsync(d_ws, 0, ((size_t)NDST*OUT_DIM + (size_t)NDST*HEADS)*sizeof(float), stream);

    build_A_kernel<<<1, 128, 0, stream>>>(q, k_w1, k_b1, C, At);
    prepack_B_kernel<<<20, 256, 0, stream>>>(k_w0, v_w0, Bph, Bpl);
    edge_kernel<<<NE/32, 256, 0, stream>>>(x_src, x_dst, e_attr, eidx,
                                           k_b0, v_b0, v_w1, v_b1,
                                           Bph, Bpl, At, C, acc_g, denom_g);
    node_kernel<<<NDST/32, 256, 0, stream>>>(acc_g, denom_g,
                                             o_w0, o_b0, o_w1, o_b1, out);
}